// Round 5
// baseline (329.119 us; speedup 1.0000x reference)
//
#include <hip/hip_runtime.h>
#include <stdint.h>

#define DIM 64
#define NE 2048
#define NROWS 65536
#define HW 4096
#define BR 256          // rows per block
#define TCB 256         // codes per tile
#define NTB (NE / TCB)  // 8 tiles

#define DECAYF 0.99f
#define OMDF ((float)(1.0 - 0.99))
#define EPSF 1e-5f
#define NEPSF ((float)(2048.0 * 1e-5))

typedef const __attribute__((address_space(1))) uint32_t* gas1_t;
typedef __attribute__((address_space(3))) uint32_t* las3_t;

__device__ __forceinline__ void gload16(const float* g, float* l) {
  __builtin_amdgcn_global_load_lds((gas1_t)g, (las3_t)l, 16, 0, 0);
}

// ---------------- se[j] = sum_d E[d][j]^2 ----------------
__global__ __launch_bounds__(256) void se_kernel(const float* __restrict__ E,
                                                 float* __restrict__ se) {
  int j = blockIdx.x * 256 + threadIdx.x;
  float s = 0.f;
#pragma unroll
  for (int d = 0; d < DIM; ++d) {
    float v = E[d * NE + j];
    s += v * v;
  }
  se[j] = s;
}

// ---------------- argmin: 256x256 tile, 512 thr, 16x8/thread ------------
// 8 waves (2/SIMD). Xs + single-buffered Es = 128 KB. Next E tile is
// prefetched to registers during compute (T14 async-STAGE), ds_written
// after the read-done barrier. Serial d-chain: bit-identical to v2-v4.
__global__ __launch_bounds__(512, 2) void argmin_kernel(const float* __restrict__ x,
                                                        const float* __restrict__ E,
                                                        const float* __restrict__ se,
                                                        int* __restrict__ ind,
                                                        float* __restrict__ ind_f) {
  __shared__ float Xs[DIM][BR];    // 64 KB
  __shared__ float Es[DIM][TCB];   // 64 KB
  const int tid = threadIdx.x;
  const int rg = tid >> 5;   // 0..15 -> rows rg*16..+16
  const int cg = tid & 31;   // 0..31 -> codes cg*4 + {0..3} (+128)
  const int B0 = blockIdx.x * BR;
  const float* xb = x + (size_t)(B0 >> 12) * (DIM * HW) + (B0 & 4095);

  // stage Xs: [64][256] floats, 8 chunks of 512thr x 16B
#pragma unroll
  for (int k = 0; k < 8; ++k) {
    int flat = k * 2048 + tid * 4;
    int d = flat >> 8, r = flat & 255;
    gload16(xb + d * HW + r, &Xs[0][0] + flat);
  }
  // stage Es tile 0
#pragma unroll
  for (int k = 0; k < 8; ++k) {
    int flat = k * 2048 + tid * 4;
    int d = flat >> 8, c = flat & 255;
    gload16(E + d * NE + c, &Es[0][0] + flat);
  }

  float bv[16];
  int bi[16];
#pragma unroll
  for (int i = 0; i < 16; ++i) { bv[i] = 3.4e38f; bi[i] = 0; }

  for (int t = 0; t < NTB; ++t) {
    __syncthreads();   // tile t resident in Es (drains vmcnt/lgkm writes)

    float4 pf[8];      // prefetch tile t+1 into registers; lands during compute
    if (t + 1 < NTB) {
#pragma unroll
      for (int k = 0; k < 8; ++k) {
        int flat = k * 2048 + tid * 4;
        int d = flat >> 8, c = flat & 255;
        pf[k] = *(const float4*)(E + d * NE + (t + 1) * TCB + c);
      }
    }

    float acc[16][8];
#pragma unroll
    for (int i = 0; i < 16; ++i)
#pragma unroll
      for (int j = 0; j < 8; ++j) acc[i][j] = 0.f;

#pragma unroll 2
    for (int d = 0; d < DIM; ++d) {   // serial d-chain: same rounding as v1-v4
      float4 x0 = *(const float4*)&Xs[d][rg * 16];
      float4 x1 = *(const float4*)&Xs[d][rg * 16 + 4];
      float4 x2 = *(const float4*)&Xs[d][rg * 16 + 8];
      float4 x3 = *(const float4*)&Xs[d][rg * 16 + 12];
      float4 e0 = *(const float4*)&Es[d][cg * 4];
      float4 e1 = *(const float4*)&Es[d][cg * 4 + 128];
      float xr[16] = {x0.x, x0.y, x0.z, x0.w, x1.x, x1.y, x1.z, x1.w,
                      x2.x, x2.y, x2.z, x2.w, x3.x, x3.y, x3.z, x3.w};
      float er[8] = {e0.x, e0.y, e0.z, e0.w, e1.x, e1.y, e1.z, e1.w};
#pragma unroll
      for (int i = 0; i < 16; ++i)
#pragma unroll
        for (int j = 0; j < 8; ++j) acc[i][j] = fmaf(xr[i], er[j], acc[i][j]);
    }

    float4 s0 = *(const float4*)(se + t * TCB + cg * 4);
    float4 s1 = *(const float4*)(se + t * TCB + cg * 4 + 128);
    float sv[8] = {s0.x, s0.y, s0.z, s0.w, s1.x, s1.y, s1.z, s1.w};
#pragma unroll
    for (int i = 0; i < 16; ++i) {
#pragma unroll
      for (int j = 0; j < 8; ++j) {
        float dist = fmaf(-2.f, acc[i][j], sv[j]);
        if (dist < bv[i]) {
          bv[i] = dist;
          bi[i] = t * TCB + (j >> 2) * 128 + cg * 4 + (j & 3);
        }
      }
    }

    __syncthreads();   // all reads of Es tile t complete
    if (t + 1 < NTB) {
#pragma unroll
      for (int k = 0; k < 8; ++k) {
        int flat = k * 2048 + tid * 4;
        *(float4*)(&Es[0][0] + flat) = pf[k];   // vmcnt waited by dependency
      }
    }
  }

  // reduce over the 32 cg-lanes of each row group (in-wave, lowest-idx ties)
#pragma unroll
  for (int i = 0; i < 16; ++i) {
    float v = bv[i];
    int ix = bi[i];
#pragma unroll
    for (int off = 1; off < 32; off <<= 1) {
      float ov = __shfl_xor(v, off, 64);
      int oi = __shfl_xor(ix, off, 64);
      if (ov < v || (ov == v && oi < ix)) { v = ov; ix = oi; }
    }
    bv[i] = v;
    bi[i] = ix;
  }
  if (cg == 0) {
#pragma unroll
    for (int i = 0; i < 16; ++i) {
      int grow = B0 + rg * 16 + i;
      ind[grow] = bi[i];
      ind_f[grow] = (float)bi[i];
    }
  }
}

// ---------------- out (NCHW) + diff ----------------
__global__ __launch_bounds__(256) void outdiff_kernel(const float* __restrict__ x,
                                                      const float* __restrict__ E,
                                                      const int* __restrict__ ind,
                                                      float* __restrict__ out,
                                                      float* __restrict__ diff_acc) {
  const int t = threadIdx.x;
  float local = 0.f;
  const int base = blockIdx.x * 1024;
#pragma unroll
  for (int u = 0; u < 4; ++u) {
    int i = base + u * 256 + t;
    int hw = i & 4095;
    int bc = i >> 12;
    int c = bc & 63;
    int b = bc >> 6;
    int idx = ind[b * 4096 + hw];
    float xv = x[i];
    float qv = E[c * NE + idx];
    float dq = qv - xv;
    out[i] = xv + dq;
    local += dq * dq;
  }
#pragma unroll
  for (int off = 32; off > 0; off >>= 1) local += __shfl_down(local, off, 64);
  __shared__ float wsum[4];
  if ((t & 63) == 0) wsum[t >> 6] = local;
  __syncthreads();
  if (t == 0) {
    float s = wsum[0] + wsum[1] + wsum[2] + wsum[3];
    atomicAdd(diff_acc, s * (1.f / 4194304.f));
  }
}

// ---------------- esum/counts via per-d-plane LDS histograms ------------
__global__ __launch_bounds__(256) void esum_kernel(const float* __restrict__ x,
                                                   const int* __restrict__ ind,
                                                   float* __restrict__ pesum,
                                                   int* __restrict__ pcnt) {
  const int d = blockIdx.x >> 2;
  const int bg = blockIdx.x & 3;
  __shared__ float h[4][NE];   // 32 KB
  __shared__ int cnt[NE];      // 8 KB
  const int tid = threadIdx.x;
  const int w = tid >> 6;
  float* hf = &h[0][0];
#pragma unroll
  for (int u = 0; u < 32; ++u) hf[u * 256 + tid] = 0.f;
  if (d == 0) {
#pragma unroll
    for (int u = 0; u < 8; ++u) cnt[u * 256 + tid] = 0;
  }
  __syncthreads();
  for (int b = bg * 4; b < bg * 4 + 4; ++b) {
    const int* ib = ind + b * 4096;
    const float* xb = x + ((size_t)b * DIM + d) * 4096;
#pragma unroll 4
    for (int it = 0; it < 16; ++it) {
      int i = it * 256 + tid;
      int idx = ib[i];
      float xv = xb[i];
      atomicAdd(&h[w][idx], xv);
      if (d == 0) atomicAdd(&cnt[idx], 1);
    }
  }
  __syncthreads();
  float* pe = pesum + ((size_t)bg * DIM + d) * NE;
#pragma unroll
  for (int u = 0; u < 8; ++u) {
    int j = u * 256 + tid;
    pe[j] = (h[0][j] + h[1][j]) + (h[2][j] + h[3][j]);
  }
  if (d == 0) {
    int* pc = pcnt + bg * NE;
#pragma unroll
    for (int u = 0; u < 8; ++u) {
      int j = u * 256 + tid;
      pc[j] = cnt[j];
    }
  }
}

// ---------------- finalize: new_cluster_size + n (partial counts) -------
__global__ __launch_bounds__(1024) void finalize_a4(const float* __restrict__ cs_in,
                                                    const int* __restrict__ pcnt,
                                                    float* __restrict__ ncs_slot,
                                                    float* __restrict__ n_out) {
  const int t = threadIdx.x;
  float local = 0.f;
#pragma unroll
  for (int u = 0; u < 2; ++u) {
    int k = u * 1024 + t;
    int c = (pcnt[k] + pcnt[NE + k]) + (pcnt[2 * NE + k] + pcnt[3 * NE + k]);
    float v = DECAYF * cs_in[k] + OMDF * (float)c;
    ncs_slot[k] = v;
    local += v;
  }
#pragma unroll
  for (int off = 32; off > 0; off >>= 1) local += __shfl_down(local, off, 64);
  __shared__ float red[16];
  if ((t & 63) == 0) red[t >> 6] = local;
  __syncthreads();
  if (t == 0) {
    float s = 0.f;
#pragma unroll
    for (int k = 0; k < 16; ++k) s += red[k];
    *n_out = s;
  }
}

// ---------------- finalize: new_embed_avg + new_embed (partial esum) ----
__global__ __launch_bounds__(256) void finalize_b4(const float* __restrict__ ea_in,
                                                   const float* __restrict__ pesum,
                                                   const float* __restrict__ ncs_slot,
                                                   const float* __restrict__ n_out,
                                                   float* __restrict__ nea_slot,
                                                   float* __restrict__ ne_slot) {
  const int k = blockIdx.x * 256 + threadIdx.x;  // 131072
  const float n = *n_out;
  const size_t P = (size_t)DIM * NE;
  float es = (pesum[k] + pesum[P + k]) + (pesum[2 * P + k] + pesum[3 * P + k]);
  float nea = DECAYF * ea_in[k] + OMDF * es;
  nea_slot[k] = nea;
  float ncs = ncs_slot[k & (NE - 1)];
  float cs = (ncs + EPSF) / (n + NEPSF) * n;
  ne_slot[k] = nea / cs;
}

// ---------------- fallback (tiny workspace): atomic scatter -------------
__global__ __launch_bounds__(256) void scatter_atomic_kernel(const float* __restrict__ x,
                                                             const int* __restrict__ ind,
                                                             float* __restrict__ counts,
                                                             float* __restrict__ esum) {
  const int row = blockIdx.x * 256 + threadIdx.x;
  const int idx = ind[row];
  atomicAdd(&counts[idx], 1.f);
  const int b = row >> 12;
  const int hw = row & 4095;
  const float* xr = x + (size_t)b * (DIM * HW) + hw;
#pragma unroll
  for (int d = 0; d < DIM; ++d) atomicAdd(&esum[d * NE + idx], xr[d * HW]);
}

__global__ __launch_bounds__(1024) void finalize_a_float(const float* __restrict__ cs_in,
                                                         float* __restrict__ ncs_slot,
                                                         float* __restrict__ n_out) {
  const int t = threadIdx.x;
  float local = 0.f;
#pragma unroll
  for (int u = 0; u < 2; ++u) {
    int k = u * 1024 + t;
    float v = DECAYF * cs_in[k] + OMDF * ncs_slot[k];
    ncs_slot[k] = v;
    local += v;
  }
#pragma unroll
  for (int off = 32; off > 0; off >>= 1) local += __shfl_down(local, off, 64);
  __shared__ float red[16];
  if ((t & 63) == 0) red[t >> 6] = local;
  __syncthreads();
  if (t == 0) {
    float s = 0.f;
#pragma unroll
    for (int k = 0; k < 16; ++k) s += red[k];
    *n_out = s;
  }
}

__global__ __launch_bounds__(256) void finalize_b_inplace(const float* __restrict__ ea_in,
                                                          float* __restrict__ nea_slot,
                                                          const float* __restrict__ ncs_slot,
                                                          const float* __restrict__ n_out,
                                                          float* __restrict__ ne_slot) {
  const int k = blockIdx.x * 256 + threadIdx.x;
  const float n = *n_out;
  float nea = DECAYF * ea_in[k] + OMDF * nea_slot[k];
  nea_slot[k] = nea;
  float ncs = ncs_slot[k & (NE - 1)];
  float cs = (ncs + EPSF) / (n + NEPSF) * n;
  ne_slot[k] = nea / cs;
}

extern "C" void kernel_launch(void* const* d_in, const int* in_sizes, int n_in,
                              void* d_out, int out_size, void* d_ws, size_t ws_size,
                              hipStream_t stream) {
  const float* x = (const float*)d_in[0];      // [16,64,64,64]
  const float* E = (const float*)d_in[1];      // [64,2048]
  const float* cs_in = (const float*)d_in[2];  // [2048]
  const float* ea_in = (const float*)d_in[3];  // [64,2048]
  float* out = (float*)d_out;

  const size_t O_OUT = 0;
  const size_t O_DIFF = 4194304;
  const size_t O_IND = 4194305;
  const size_t O_NE = 4259841;    // new_embed [64,2048]
  const size_t O_NCS = 4390913;   // new_cluster_size [2048]
  const size_t O_NEA = 4392961;   // new_embed_avg [64,2048]

  // workspace layout
  float* se = (float*)d_ws;                  // 2048
  int* ind = (int*)(se + NE);                // 65536
  float* n_out = (float*)(ind + NROWS);      // 1 (+3 pad)
  int* pcnt = (int*)(n_out + 4);             // 4*2048
  float* pesum = (float*)(pcnt + 4 * NE);    // 4*131072
  const size_t need = (size_t)((char*)(pesum + 4 * (size_t)DIM * NE) - (char*)d_ws);
  const bool big_ws = ws_size >= need;

  hipMemsetAsync(out + O_DIFF, 0, 4, stream);

  se_kernel<<<NE / 256, 256, 0, stream>>>(E, se);
  argmin_kernel<<<NROWS / BR, 512, 0, stream>>>(x, E, se, ind, out + O_IND);
  outdiff_kernel<<<4096, 256, 0, stream>>>(x, E, ind, out + O_OUT, out + O_DIFF);

  if (big_ws) {
    esum_kernel<<<DIM * 4, 256, 0, stream>>>(x, ind, pesum, pcnt);
    finalize_a4<<<1, 1024, 0, stream>>>(cs_in, pcnt, out + O_NCS, n_out);
    finalize_b4<<<DIM * NE / 256, 256, 0, stream>>>(ea_in, pesum, out + O_NCS, n_out,
                                                    out + O_NEA, out + O_NE);
  } else {
    hipMemsetAsync(out + O_NCS, 0, NE * 4, stream);
    hipMemsetAsync(out + O_NEA, 0, (size_t)DIM * NE * 4, stream);
    scatter_atomic_kernel<<<NROWS / 256, 256, 0, stream>>>(x, ind, out + O_NCS,
                                                           out + O_NEA);
    finalize_a_float<<<1, 1024, 0, stream>>>(cs_in, out + O_NCS, n_out);
    finalize_b_inplace<<<DIM * NE / 256, 256, 0, stream>>>(ea_in, out + O_NEA,
                                                           out + O_NCS, n_out,
                                                           out + O_NE);
  }
}